// Round 5
// baseline (282.568 us; speedup 1.0000x reference)
//
#include <hip/hip_runtime.h>
#include <stdint.h>

// Problem constants
#define NLAYERS 32
#define DSIZE   1024
#define OSIZE   1024
#define BATCH   32
#define SEQ     256

// ws layout (ints): [0]=nchunks; [16..272)=perm; [512 + 4*c ..]=chunk{layer, rank_base, nranks, pad}
#define WS_PERM  16
#define WS_TILE  512
#define CHUNK    4      // seq positions per m-chunk -> 128 m-rows (4 ranks x 32 batch)
#define MAXC     88     // sum ceil(cnt/4) <= 64 + 24 = 88
#define BK       32
#define TM       128
#define TN       128
#define THREADS  256
#define KITERS   (DSIZE / BK)   // 32

typedef __attribute__((ext_vector_type(8)))  short short8;
typedef __attribute__((ext_vector_type(16))) float f32x16;
typedef __attribute__((ext_vector_type(4)))  unsigned uint4v;

__global__ void prep_kernel(const int* __restrict__ layer_idx, int* __restrict__ wsi) {
    __shared__ int cnt[NLAYERS];
    __shared__ int start_[NLAYERS];
    __shared__ int cursor[NLAYERS];
    const int t = threadIdx.x;
    if (t < NLAYERS) cnt[t] = 0;
    __syncthreads();
    int l = 0;
    if (t < SEQ) { l = layer_idx[t]; atomicAdd(&cnt[l], 1); }
    __syncthreads();
    if (t == 0) {
        int acc = 0;
        for (int i = 0; i < NLAYERS; ++i) { start_[i] = acc; cursor[i] = acc; acc += cnt[i]; }
    }
    __syncthreads();
    if (t < SEQ) {
        int r = atomicAdd(&cursor[l], 1);
        wsi[WS_PERM + r] = t;           // perm[rank] = s
    }
    if (t == 0) {
        int nc = 0;
        for (int i = 0; i < NLAYERS; ++i) {
            const int c = cnt[i];
            for (int j = 0; j < c; j += CHUNK) {
                wsi[WS_TILE + nc*4 + 0] = i;
                wsi[WS_TILE + nc*4 + 1] = start_[i] + j;
                wsi[WS_TILE + nc*4 + 2] = (c - j < CHUNK) ? (c - j) : CHUNK;
                ++nc;
            }
        }
        wsi[0] = nc;   // <= 88
    }
}

// round-to-nearest-up fp32->bf16 pair pack: low16 = bf16(a), high16 = bf16(b)
static __device__ __forceinline__ unsigned pk2(float a, float b) {
    unsigned ua = __builtin_bit_cast(unsigned, a) + 0x8000u;
    unsigned ub = __builtin_bit_cast(unsigned, b) + 0x8000u;
    return __builtin_amdgcn_perm(ub, ua, 0x07060302u);  // {ua[2],ua[3],ub[2],ub[3]}
}

// Tile: 128 m-rows (4 ranks x 32 batch) x 128 o-cols, BK=32, 4 waves (2m x 2n),
// wave tile 64x64, acc = 2x2 of 32x32 (64 AGPR). Stage 32 VGPR -> ~115 total
// -> 4 waves/SIMD tier; LDS 32KB dbuf -> 4 independent blocks/CU = 16 waves/CU
// in 4 separate barrier domains (R0's proven high-effective-BW regime).
// LDS row = 32 bf16 (64B) = 4 granules of 16B; granule g of row r stored at
// g ^ ((r>>1)&3): bank-group k = (4r + g') mod 8 then covers all 8 groups per
// 8 rows on reads AND writes -> min-cycle (8 cy) ds_read/write_b128.
// Grid: fid = g*8 + ntile; consecutive fids = same chunk, different ntile ->
// round-robin across XCDs: A-slab replicated in every XCD L2 (hot, 32MB total);
// blocks sharing (layer,ntile) B-slab land on the same XCD (fid%8 = ntile).
__global__ __launch_bounds__(THREADS, 4) void gemm_kernel(
        const float* __restrict__ x, const float* __restrict__ wgt,
        const int* __restrict__ wsi, float* __restrict__ out) {
    const int fid   = blockIdx.x;
    const int g     = fid >> 3;
    const int ntile = fid & 7;                // o block of 128
    const int nchunks = wsi[0];
    if (g >= nchunks) return;
    const int layer     = wsi[WS_TILE + g*4 + 0];
    const int rank_base = wsi[WS_TILE + g*4 + 1];
    const int nranks    = wsi[WS_TILE + g*4 + 2];      // 1..4

    __shared__ __align__(16) short ldsA[2][TM * BK];
    __shared__ __align__(16) short ldsB[2][TN * BK];

    const int t    = threadIdx.x;
    // ---- staging mapping: slot = 16B LDS granule (8 k-elems = 32B fp32 source)
    const int slot = t & 3;
    const int rb   = t >> 2;          // 0..63
    const int wsw  = ((slot ^ ((rb >> 1) & 3)) << 3);   // swizzled granule offset (shorts)

    const float* aptr[2];
    bool av[2];
    #pragma unroll
    for (int p = 0; p < 2; ++p) {
        const int r  = rb + 64*p;
        const int ro = r >> 5;        // rank 0..3
        const int b  = r & 31;        // batch
        av[p] = (ro < nranks);
        const int s = av[p] ? wsi[WS_PERM + rank_base + ro] : 0;
        aptr[p] = x + (((size_t)(b * SEQ + s)) << 10) + slot*8;
    }
    const float* bptr = wgt + ((size_t)layer << 20)
                            + (((size_t)(ntile * TN + rb)) << 10) + slot*8;

    float4 ra[2][2], rbv[2][2];
    // issue A first, then B: compiler's auto-vmcnt lets storeA wait only for A
    auto load_step = [&](int kk) {
        #pragma unroll
        for (int p = 0; p < 2; ++p) {
            if (av[p]) {
                ra[p][0] = *(const float4*)(aptr[p] + kk);
                ra[p][1] = *(const float4*)(aptr[p] + kk + 4);
            }
        }
        #pragma unroll
        for (int p = 0; p < 2; ++p) {
            rbv[p][0] = *(const float4*)(bptr + ((size_t)p << 16) + kk);
            rbv[p][1] = *(const float4*)(bptr + ((size_t)p << 16) + kk + 4);
        }
    };
    auto storeA = [&](int buf) {
        #pragma unroll
        for (int p = 0; p < 2; ++p) {
            if (av[p]) {
                uint4v u4;
                u4.x = pk2(ra[p][0].x, ra[p][0].y);
                u4.y = pk2(ra[p][0].z, ra[p][0].w);
                u4.z = pk2(ra[p][1].x, ra[p][1].y);
                u4.w = pk2(ra[p][1].z, ra[p][1].w);
                *(uint4v*)&ldsA[buf][(rb + 64*p) * BK + wsw] = u4;
            }
        }
    };
    auto storeB = [&](int buf) {
        #pragma unroll
        for (int p = 0; p < 2; ++p) {
            uint4v u4;
            u4.x = pk2(rbv[p][0].x, rbv[p][0].y);
            u4.y = pk2(rbv[p][0].z, rbv[p][0].w);
            u4.z = pk2(rbv[p][1].x, rbv[p][1].y);
            u4.w = pk2(rbv[p][1].z, rbv[p][1].w);
            *(uint4v*)&ldsB[buf][(rb + 64*p) * BK + wsw] = u4;
        }
    };

    // ---- compute mapping: 4 waves as 2(m) x 2(n), wave tile 64x64
    const int lane = t & 63;
    const int wv   = t >> 6;
    const int l31  = lane & 31;
    const int lh   = lane >> 5;
    const int am   = (wv >> 1) << 6;   // 0,64
    const int bn   = (wv & 1) << 6;    // 0,64
    const int rsw  = (l31 >> 1) & 3;   // read-side swizzle ((row>>1)&3)

    const int baseA0 = (am +  0 + l31) * BK;
    const int baseA1 = (am + 32 + l31) * BK;
    const int baseB0 = (bn +  0 + l31) * BK;
    const int baseB1 = (bn + 32 + l31) * BK;

    const int rank0 = am >> 5;         // 0 or 2
    const bool ok0 = (rank0 + 0) < nranks;
    const bool ok1 = (rank0 + 1) < nranks;

    f32x16 acc[2][2];
    #pragma unroll
    for (int mi = 0; mi < 2; ++mi)
        #pragma unroll
        for (int ni = 0; ni < 2; ++ni)
            #pragma unroll
            for (int r = 0; r < 16; ++r) acc[mi][ni][r] = 0.f;

    // prologue: fill buf0
    load_step(0);
    storeA(0);
    storeB(0);
    __syncthreads();

    #pragma unroll 1
    for (int kt = 0; kt < KITERS; ++kt) {
        const int cur = kt & 1;
        const bool more = (kt + 1 < KITERS);
        if (more) load_step((kt + 1) * BK);   // A then B, in flight during MFMA
        // ---- sub-step 0 (overlaps A-load latency)
        {
            const int gx = ((0*2 + lh) ^ rsw) << 3;
            short8 b0 = *(const short8*)&ldsB[cur][baseB0 + gx];
            short8 b1 = *(const short8*)&ldsB[cur][baseB1 + gx];
            if (ok0) {
                short8 a0 = *(const short8*)&ldsA[cur][baseA0 + gx];
                acc[0][0] = __builtin_amdgcn_mfma_f32_32x32x16_bf16(a0, b0, acc[0][0], 0, 0, 0);
                acc[0][1] = __builtin_amdgcn_mfma_f32_32x32x16_bf16(a0, b1, acc[0][1], 0, 0, 0);
            }
            if (ok1) {
                short8 a1 = *(const short8*)&ldsA[cur][baseA1 + gx];
                acc[1][0] = __builtin_amdgcn_mfma_f32_32x32x16_bf16(a1, b0, acc[1][0], 0, 0, 0);
                acc[1][1] = __builtin_amdgcn_mfma_f32_32x32x16_bf16(a1, b1, acc[1][1], 0, 0, 0);
            }
        }
        if (more) storeA(cur ^ 1);   // waits A loads only (issued first)
        // ---- sub-step 1 (overlaps B-load latency tail)
        {
            const int gx = ((1*2 + lh) ^ rsw) << 3;
            short8 b0 = *(const short8*)&ldsB[cur][baseB0 + gx];
            short8 b1 = *(const short8*)&ldsB[cur][baseB1 + gx];
            if (ok0) {
                short8 a0 = *(const short8*)&ldsA[cur][baseA0 + gx];
                acc[0][0] = __builtin_amdgcn_mfma_f32_32x32x16_bf16(a0, b0, acc[0][0], 0, 0, 0);
                acc[0][1] = __builtin_amdgcn_mfma_f32_32x32x16_bf16(a0, b1, acc[0][1], 0, 0, 0);
            }
            if (ok1) {
                short8 a1 = *(const short8*)&ldsA[cur][baseA1 + gx];
                acc[1][0] = __builtin_amdgcn_mfma_f32_32x32x16_bf16(a1, b0, acc[1][0], 0, 0, 0);
                acc[1][1] = __builtin_amdgcn_mfma_f32_32x32x16_bf16(a1, b1, acc[1][1], 0, 0, 0);
            }
        }
        if (more) {
            storeB(cur ^ 1);
            __syncthreads();
        }
    }

    // epilogue: C/D layout col = lane&31, row = (reg&3) + 8*(reg>>2) + 4*(lane>>5)
    #pragma unroll
    for (int mi = 0; mi < 2; ++mi) {
        const int ro = rank0 + mi;
        if (ro < nranks) {
            const int s = wsi[WS_PERM + rank_base + ro];
            #pragma unroll
            for (int ni = 0; ni < 2; ++ni) {
                const int ocol = ntile * TN + bn + ni*32 + l31;
                #pragma unroll
                for (int r = 0; r < 16; ++r) {
                    const int brow = (r & 3) + 8*(r >> 2) + 4*lh;  // batch b
                    out[(((size_t)(brow * SEQ + s)) << 10) + ocol] = acc[mi][ni][r];
                }
            }
        }
    }
}

extern "C" void kernel_launch(void* const* d_in, const int* in_sizes, int n_in,
                              void* d_out, int out_size, void* d_ws, size_t ws_size,
                              hipStream_t stream) {
    const float* x         = (const float*)d_in[0];
    const int*   layer_idx = (const int*)  d_in[1];
    const float* weight    = (const float*)d_in[2];
    float* out = (float*)d_out;
    int*   wsi = (int*)d_ws;

    prep_kernel<<<1, 256, 0, stream>>>(layer_idx, wsi);
    gemm_kernel<<<MAXC * 8, THREADS, 0, stream>>>(x, weight, wsi, out);
}

// Round 6
// 252.052 us; speedup vs baseline: 1.1211x; 1.1211x over previous
//
#include <hip/hip_runtime.h>
#include <hip/hip_bf16.h>
#include <stdint.h>

// Problem constants
#define NLAYERS 32
#define DSIZE   1024
#define OSIZE   1024
#define BATCH   32
#define SEQ     256

// ws layout (ints): [0]=ntiles; [16..272)=perm; [512 + 4*t ..]=tile{layer, rank_base, nranks, pad}
#define WS_PERM  16
#define WS_TILE  512
#define MAX_TILES 88   // sum ceil(cnt/4) <= 64 + 24 = 88
#define NSPLIT   16    // o-dim tiles of 64

typedef __attribute__((ext_vector_type(8)))  short short8;
typedef __attribute__((ext_vector_type(16))) float f32x16;

#define LDSTRIDE 72   // shorts per LDS row (64 + 8 pad; 144 B = 16B-aligned rows)
#define BK 64

__global__ void prep_kernel(const int* __restrict__ layer_idx, int* __restrict__ wsi) {
    __shared__ int cnt[NLAYERS];
    __shared__ int start_[NLAYERS];
    __shared__ int cursor[NLAYERS];
    const int t = threadIdx.x;
    if (t < NLAYERS) cnt[t] = 0;
    __syncthreads();
    int l = 0;
    if (t < SEQ) { l = layer_idx[t]; atomicAdd(&cnt[l], 1); }
    __syncthreads();
    if (t == 0) {
        int acc = 0;
        for (int i = 0; i < NLAYERS; ++i) { start_[i] = acc; cursor[i] = acc; acc += cnt[i]; }
    }
    __syncthreads();
    if (t < SEQ) {
        int r = atomicAdd(&cursor[l], 1);
        wsi[WS_PERM + r] = t;           // perm[rank] = s  (order within layer irrelevant)
    }
    if (t == 0) {
        int nt = 0;
        for (int i = 0; i < NLAYERS; ++i) {
            const int c = cnt[i];
            for (int j = 0; j < c; j += 4) {
                wsi[WS_TILE + nt*4 + 0] = i;
                wsi[WS_TILE + nt*4 + 1] = start_[i] + j;
                wsi[WS_TILE + nt*4 + 2] = (c - j < 4) ? (c - j) : 4;
                ++nt;
            }
        }
        wsi[0] = nt;   // 64..88
    }
}

// round-to-nearest fp32->bf16 pair pack: low16 = bf16(a), high16 = bf16(b)
static __device__ __forceinline__ unsigned pk2(float a, float b) {
    unsigned ua = __builtin_bit_cast(unsigned, a) + 0x8000u;
    unsigned ub = __builtin_bit_cast(unsigned, b) + 0x8000u;
    return __builtin_amdgcn_perm(ub, ua, 0x07060302u);  // {ua[2],ua[3],ub[2],ub[3]}
}

// Tile: 128 m-rows (4 ranks x 32 batch) x 64 o-cols, BK=64, 4 waves.
// Wave wv computes rows [32*wv, 32*wv+32) x all 64 cols -> rank roff == wv.
//
// Grid 1408 blocks, 1-D. XCD mapping (fid%8 = XCD under round-robin dispatch):
//   xcd = fid&7 owns the contiguous chunk run [xcd*nt/8, (xcd+1)*nt/8) x 16 ntiles.
// -> each XCD touches only ~1/8 of x (A L2-miss 256MB -> 32MB total);
//    same-layer chunks (adjacent in prep order) stay co-XCD -> B slab dedup in L2;
//    the 16 ntile blocks of a chunk are dispatch-adjacent on one XCD -> A slab L2-hits.
// Per-XCD hot window: 11 chunks x 32KB (A k-slab) + ~176 B-slab windows x 16KB ~ 3.2MB < 4MB L2.
__global__ __launch_bounds__(256, 3) void gemm_kernel(
        const float* __restrict__ x, const float* __restrict__ wgt,
        const int* __restrict__ wsi, float* __restrict__ out) {
    const int ntiles = wsi[0];
    const int xcd = blockIdx.x & 7;
    const int idx = blockIdx.x >> 3;                    // 0..175
    const int g_lo = (xcd * ntiles) >> 3;
    const int g_hi = ((xcd + 1) * ntiles) >> 3;
    const int nblk = (g_hi - g_lo) << 4;                // chunks-in-run * 16 ntiles
    if (idx >= nblk) return;
    const int mt    = g_lo + (idx >> 4);                // chunk id
    const int ntile = idx & 15;                         // o block of 64
    const int layer     = wsi[WS_TILE + mt*4 + 0];
    const int rank_base = wsi[WS_TILE + mt*4 + 1];
    const int nranks    = wsi[WS_TILE + mt*4 + 2];

    __shared__ __align__(16) short ldsA[128 * LDSTRIDE];
    __shared__ __align__(16) short ldsB[64 * LDSTRIDE];

    const int t     = threadIdx.x;
    // ---- coalesced staging: wave = 4 rows x 16 lanes x 16B (4 x 256B segments/instr)
    const int c4    = (t & 15) * 4;   // float (== bf16-short) column within 64-wide k-slab
    const int rbase = t >> 4;         // 0..15; pass p covers row = rbase + 16*p

    bool svalid[4];
    int  sv[4];
    #pragma unroll
    for (int j = 0; j < 4; ++j) {
        svalid[j] = (j < nranks);
        sv[j] = svalid[j] ? wsi[WS_PERM + rank_base + j] : 0;
    }

    // A rows: row = rbase + 16p (p=0..7) -> rank roff = p>>1, batch b = rbase + 16*(p&1)
    const float* aptr[8];
    #pragma unroll
    for (int p = 0; p < 8; ++p) {
        const int roff = p >> 1;
        const int b    = rbase + ((p & 1) << 4);
        aptr[p] = x + (((size_t)(b * SEQ + sv[roff])) << 10) + c4;
    }
    // B rows: orow = ntile*64 + rbase + 16p (p=0..3)
    const float* bbase = wgt + (((size_t)((layer << 10) + ntile * 64 + rbase)) << 10) + c4;

    float4 ra[8], rb[4];
    auto load_step = [&](int kk) {
        #pragma unroll
        for (int p = 0; p < 8; ++p) {
            if (svalid[p >> 1]) ra[p] = *(const float4*)(aptr[p] + kk);
            else                ra[p] = make_float4(0.f, 0.f, 0.f, 0.f);
        }
        #pragma unroll
        for (int p = 0; p < 4; ++p)
            rb[p] = *(const float4*)(bbase + ((size_t)p << 14) + kk);  // +p*16 rows
    };

    // compute-side mapping
    const int lane = t & 63;
    const int wv   = t >> 6;
    const int wm   = wv * 32;         // wave row base == rank wv
    const int l31  = lane & 31;
    const int lh   = lane >> 5;

    f32x16 acc[2];
    #pragma unroll
    for (int ni = 0; ni < 2; ++ni)
        #pragma unroll
        for (int r = 0; r < 16; ++r) acc[ni][r] = 0.f;

    const short* pA0 = &ldsA[(wm + l31) * LDSTRIDE + lh * 8];
    const short* pB0 = &ldsB[l31 * LDSTRIDE + lh * 8];

    load_step(0);
    #pragma unroll 1
    for (int kk = 0; kk < DSIZE; kk += BK) {
        __syncthreads();   // previous compute done reading LDS
        #pragma unroll
        for (int p = 0; p < 8; ++p) {
            const int row = rbase + 16 * p;
            uint2 va;
            va.x = pk2(ra[p].x, ra[p].y);
            va.y = pk2(ra[p].z, ra[p].w);
            *(uint2*)&ldsA[row * LDSTRIDE + c4] = va;
        }
        #pragma unroll
        for (int p = 0; p < 4; ++p) {
            const int row = rbase + 16 * p;
            uint2 vb;
            vb.x = pk2(rb[p].x, rb[p].y);
            vb.y = pk2(rb[p].z, rb[p].w);
            *(uint2*)&ldsB[row * LDSTRIDE + c4] = vb;
        }
        __syncthreads();
        if (kk + BK < DSIZE) load_step(kk + BK);  // prefetch overlaps MFMA below
        #pragma unroll
        for (int sub = 0; sub < 4; ++sub) {       // 4 x (K=16) sub-steps
            short8 a0 = *(const short8*)(pA0 + sub*16);
            short8 b0 = *(const short8*)(pB0 + sub*16);
            short8 b1 = *(const short8*)(pB0 + 32*LDSTRIDE + sub*16);
            acc[0] = __builtin_amdgcn_mfma_f32_32x32x16_bf16(a0, b0, acc[0], 0, 0, 0);
            acc[1] = __builtin_amdgcn_mfma_f32_32x32x16_bf16(a0, b1, acc[1], 0, 0, 0);
        }
    }

    // epilogue: C/D layout col = lane&31, row = (reg&3) + 8*(reg>>2) + 4*(lane>>5)
    if (wv < nranks) {
        const int s = wsi[WS_PERM + rank_base + wv];
        #pragma unroll
        for (int ni = 0; ni < 2; ++ni) {
            const int ocol = ntile * 64 + ni * 32 + l31;
            #pragma unroll
            for (int r = 0; r < 16; ++r) {
                const int brow = (r & 3) + 8 * (r >> 2) + 4 * lh;  // = batch b
                out[(((size_t)(brow * SEQ + s)) << 10) + ocol] = acc[ni][r];
            }
        }
    }
}

extern "C" void kernel_launch(void* const* d_in, const int* in_sizes, int n_in,
                              void* d_out, int out_size, void* d_ws, size_t ws_size,
                              hipStream_t stream) {
    const float* x         = (const float*)d_in[0];
    const int*   layer_idx = (const int*)  d_in[1];
    const float* weight    = (const float*)d_in[2];
    float* out = (float*)d_out;
    int*   wsi = (int*)d_ws;

    prep_kernel<<<1, 256, 0, stream>>>(layer_idx, wsi);
    gemm_kernel<<<MAX_TILES * NSPLIT, 256, 0, stream>>>(x, weight, wsi, out);
}